// Round 1
// baseline (456.152 us; speedup 1.0000x reference)
//
#include <hip/hip_runtime.h>

// MultiConvPerm: out[co,ci,t] over (256,256,1024) f32.
// coef = softmax(alpha + gumbels)  (log_softmax shift cancels)
// acc[s] (s in [0,57)) = sum over 72 static taps: coef[i]*w_i[pair, j] at s = p_i + j*d_i
// flip+roll collapses to: out[t] = acc[28-t] (t<=28), acc[1052-t] (t>=996), else 0.

#define NW 12

__global__ void coef_kernel(const float* __restrict__ alpha,
                            const float* __restrict__ gumbels,
                            float* __restrict__ coef) {
    int t = threadIdx.x;
    __shared__ float z[NW];
    if (t < NW) z[t] = alpha[t] + gumbels[t];
    __syncthreads();
    if (t < NW) {
        float m = z[0];
#pragma unroll
        for (int i = 1; i < NW; ++i) m = fmaxf(m, z[i]);
        float s = 0.f;
#pragma unroll
        for (int i = 0; i < NW; ++i) s += expf(z[i] - m);
        coef[t] = expf(z[t] - m) / s;
    }
}

// One block per (co,ci) pair. 256 threads -> 256 float4 = 1024 floats of output row.
__global__ __launch_bounds__(256) void multiconv_out(
    const float* __restrict__ w0,  const float* __restrict__ w1,
    const float* __restrict__ w2,  const float* __restrict__ w3,
    const float* __restrict__ w4,  const float* __restrict__ w5,
    const float* __restrict__ w6,  const float* __restrict__ w7,
    const float* __restrict__ w8,  const float* __restrict__ w9,
    const float* __restrict__ w10, const float* __restrict__ w11,
    const float* __restrict__ coef, float* __restrict__ out) {
    __shared__ float acc[57];
    __shared__ float cf[NW];
    const int tid  = threadIdx.x;
    const int pair = blockIdx.x;

    if (tid < 57) acc[tid] = 0.f;
    // wave 1 loads coefs while wave 0 zeroes acc
    if (tid >= 64 && tid < 64 + NW) cf[tid - 64] = coef[tid - 64];
    __syncthreads();

    // taps: (k, dilation d) -> length L = d*(k-1)+1, left pad p = (57-L)/2,
    // tap j lands at s = p + j*d. Lanes 0..k-1 of wave 0 do the adds; within one
    // unrolled step addresses are distinct; cross-step overlap handled by LDS atomics.
#define TAP(WP, I, K, P, D) \
    if (tid < (K)) atomicAdd(&acc[(P) + tid * (D)], cf[I] * WP[pair * (K) + tid]);
    TAP(w0,  0, 3, 27, 1)
    TAP(w1,  1, 3, 25, 3)
    TAP(w2,  2, 3, 21, 7)
    TAP(w3,  3, 5, 26, 1)
    TAP(w4,  4, 5, 22, 3)
    TAP(w5,  5, 5, 14, 7)
    TAP(w6,  6, 7, 25, 1)
    TAP(w7,  7, 7, 19, 3)
    TAP(w8,  8, 7,  7, 7)
    TAP(w9,  9, 9, 24, 1)
    TAP(w10, 10, 9, 16, 3)
    TAP(w11, 11, 9,  0, 7)
#undef TAP
    __syncthreads();

    float4 v; v.x = v.y = v.z = v.w = 0.f;
    if (tid < 8) {
        int t0 = tid * 4;                 // t in [0,31]; nonzero for t<=28: s = 28-t
        v.x = acc[28 - t0];
        if (tid < 7) {
            v.y = acc[27 - t0];
            v.z = acc[26 - t0];
            v.w = acc[25 - t0];
        }
    } else if (tid >= 249) {
        int t0 = tid * 4;                 // t in [996,1023]: s = 1052-t (29..56)
        v.x = acc[1052 - t0];
        v.y = acc[1051 - t0];
        v.z = acc[1050 - t0];
        v.w = acc[1049 - t0];
    }
    reinterpret_cast<float4*>(out)[(long)pair * 256 + tid] = v;
}

extern "C" void kernel_launch(void* const* d_in, const int* in_sizes, int n_in,
                              void* d_out, int out_size, void* d_ws, size_t ws_size,
                              hipStream_t stream) {
    const float* alpha   = (const float*)d_in[12];
    const float* gumbels = (const float*)d_in[13];
    float* coef = (float*)d_ws;   // 12 floats of scratch

    coef_kernel<<<1, 64, 0, stream>>>(alpha, gumbels, coef);

    multiconv_out<<<256 * 256, 256, 0, stream>>>(
        (const float*)d_in[0], (const float*)d_in[1], (const float*)d_in[2],
        (const float*)d_in[3], (const float*)d_in[4], (const float*)d_in[5],
        (const float*)d_in[6], (const float*)d_in[7], (const float*)d_in[8],
        (const float*)d_in[9], (const float*)d_in[10], (const float*)d_in[11],
        coef, (float*)d_out);
}

// Round 3
// 349.899 us; speedup vs baseline: 1.3037x; 1.3037x over previous
//
#include <hip/hip_runtime.h>

// MultiConvPerm: out[co,ci,t] over (256,256,1024) f32.
// coef = softmax(alpha + gumbels)  (log_softmax shift cancels under softmax)
// acc[s], s in [0,57): sum of 72 static taps coef[i]*w_i[pair,j] at s = p_i + j*d_i
// flip+roll collapses to: out[t] = acc[28-t] (t<=28), acc[1052-t] (t>=996), else 0.
// => per 256-float4 row, only slots 0..7 and 249..255 are nonzero (15 of 256).
// Strategy: fat streaming zerofill of the whole buffer, then a sparse kernel
// that computes and overwrites only the nonzero slots.

#define NW 12
#define PAIRS_PER_BLOCK 16

typedef float vfloat4 __attribute__((ext_vector_type(4)));

__global__ __launch_bounds__(256) void zerofill(vfloat4* __restrict__ out, int n4) {
    const int stride = gridDim.x * blockDim.x;
    vfloat4 z = (vfloat4)0.f;
    for (int i = blockIdx.x * blockDim.x + threadIdx.x; i < n4; i += stride)
        __builtin_nontemporal_store(z, &out[i]);
}

__global__ __launch_bounds__(256) void sparse_taps(
    const float* __restrict__ w0,  const float* __restrict__ w1,
    const float* __restrict__ w2,  const float* __restrict__ w3,
    const float* __restrict__ w4,  const float* __restrict__ w5,
    const float* __restrict__ w6,  const float* __restrict__ w7,
    const float* __restrict__ w8,  const float* __restrict__ w9,
    const float* __restrict__ w10, const float* __restrict__ w11,
    const float* __restrict__ alpha, const float* __restrict__ gumbels,
    float* __restrict__ out) {
    __shared__ float acc[PAIRS_PER_BLOCK][57];
    __shared__ float cf[NW];
    const int tid = threadIdx.x;
    const int p0  = blockIdx.x * PAIRS_PER_BLOCK;

    // zero the accumulator tile
    float* af = &acc[0][0];
    for (int i = tid; i < PAIRS_PER_BLOCK * 57; i += 256) af[i] = 0.f;

    // redundant per-block softmax (alpha/gumbels are 12 floats, L2-hot)
    if (tid < NW) {
        float m = -1e30f;
#pragma unroll
        for (int i = 0; i < NW; ++i) m = fmaxf(m, alpha[i] + gumbels[i]);
        float s = 0.f;
#pragma unroll
        for (int i = 0; i < NW; ++i) s += expf(alpha[i] + gumbels[i] - m);
        cf[tid] = expf(alpha[tid] + gumbels[tid] - m) / s;
    }
    __syncthreads();

    // Coalesced weight loads: threads t < 16*k read w_i[p0*k + t] contiguously.
    // pair_local = t/k, tap j = t%k; tap lands at s = p + j*d.
    // Cross-array overlaps at the same (pair,s) are resolved by LDS atomics.
#define TAP(WP, I, K, P, D)                                                   \
    if (tid < PAIRS_PER_BLOCK * (K)) {                                        \
        int pl = tid / (K), j = tid % (K);                                    \
        atomicAdd(&acc[pl][(P) + j * (D)],                                    \
                  cf[I] * WP[(size_t)p0 * (K) + tid]);                        \
    }
    TAP(w0,  0, 3, 27, 1)
    TAP(w1,  1, 3, 25, 3)
    TAP(w2,  2, 3, 21, 7)
    TAP(w3,  3, 5, 26, 1)
    TAP(w4,  4, 5, 22, 3)
    TAP(w5,  5, 5, 14, 7)
    TAP(w6,  6, 7, 25, 1)
    TAP(w7,  7, 7, 19, 3)
    TAP(w8,  8, 7,  7, 7)
    TAP(w9,  9, 9, 24, 1)
    TAP(w10, 10, 9, 16, 3)
    TAP(w11, 11, 9,  0, 7)
#undef TAP
    __syncthreads();

    // 16 threads per pair; 15 write the nonzero float4 slots.
    const int pl = tid >> 4;
    const int sl = tid & 15;
    if (sl < 15) {
        const float* a = acc[pl];
        vfloat4 v;
        int slot;
        if (sl < 7) {                       // slots 0..6: t = 4*sl..4*sl+3, s = 28-t
            int t0 = sl * 4;
            v.x = a[28 - t0]; v.y = a[27 - t0]; v.z = a[26 - t0]; v.w = a[25 - t0];
            slot = sl;
        } else if (sl == 7) {               // slot 7: t=28 -> s=0; t=29..31 zero
            v.x = a[0]; v.y = 0.f; v.z = 0.f; v.w = 0.f;
            slot = 7;
        } else {                            // sl 8..14 -> slots 249..255, s = 1052-t
            slot = 241 + sl;
            int t0 = slot * 4;
            v.x = a[1052 - t0]; v.y = a[1051 - t0]; v.z = a[1050 - t0]; v.w = a[1049 - t0];
        }
        reinterpret_cast<vfloat4*>(out)[(size_t)(p0 + pl) * 256 + slot] = v;
    }
}

extern "C" void kernel_launch(void* const* d_in, const int* in_sizes, int n_in,
                              void* d_out, int out_size, void* d_ws, size_t ws_size,
                              hipStream_t stream) {
    float* out = (float*)d_out;
    const int n4 = (256 * 256 * 1024) / 4;  // 16.78M float4

    zerofill<<<2048, 256, 0, stream>>>((vfloat4*)out, n4);

    sparse_taps<<<(256 * 256) / PAIRS_PER_BLOCK, 256, 0, stream>>>(
        (const float*)d_in[0], (const float*)d_in[1], (const float*)d_in[2],
        (const float*)d_in[3], (const float*)d_in[4], (const float*)d_in[5],
        (const float*)d_in[6], (const float*)d_in[7], (const float*)d_in[8],
        (const float*)d_in[9], (const float*)d_in[10], (const float*)d_in[11],
        (const float*)d_in[12], (const float*)d_in[13], out);
}

// Round 4
// 324.119 us; speedup vs baseline: 1.4074x; 1.0795x over previous
//
#include <hip/hip_runtime.h>

// MultiConvPerm: out[co,ci,t] over (256,256,1024) f32, fused single pass.
// coef = softmax(alpha + gumbels)  (log_softmax shift cancels under softmax)
// acc[s], s in [0,57): sum of 72 static taps coef[i]*w_i[pair,j] at s = p_i + j*d_i
// flip+roll collapses to: out[t] = acc[28-t] (t<=28), acc[1052-t] (t>=996), else 0.
// Per 256-float4 row only slots 0..7 and 249..255 are nonzero; all slots are
// streamed out in one pass (268 MB nontemporal writes), values gathered from LDS.

#define NW 12
#define PAIRS_PER_BLOCK 16

typedef float vfloat4 __attribute__((ext_vector_type(4)));

__global__ __launch_bounds__(256) void multiconv_fused(
    const float* __restrict__ w0,  const float* __restrict__ w1,
    const float* __restrict__ w2,  const float* __restrict__ w3,
    const float* __restrict__ w4,  const float* __restrict__ w5,
    const float* __restrict__ w6,  const float* __restrict__ w7,
    const float* __restrict__ w8,  const float* __restrict__ w9,
    const float* __restrict__ w10, const float* __restrict__ w11,
    const float* __restrict__ alpha, const float* __restrict__ gumbels,
    float* __restrict__ out) {
    __shared__ float acc[PAIRS_PER_BLOCK][57];
    __shared__ float cf[NW];
    const int tid = threadIdx.x;
    const int p0  = blockIdx.x * PAIRS_PER_BLOCK;

    // zero the accumulator tile
    float* af = &acc[0][0];
    for (int i = tid; i < PAIRS_PER_BLOCK * 57; i += 256) af[i] = 0.f;

    // redundant per-block softmax (alpha/gumbels are 12 floats, L2-hot)
    if (tid < NW) {
        float m = -1e30f;
#pragma unroll
        for (int i = 0; i < NW; ++i) m = fmaxf(m, alpha[i] + gumbels[i]);
        float s = 0.f;
#pragma unroll
        for (int i = 0; i < NW; ++i) s += expf(alpha[i] + gumbels[i] - m);
        cf[tid] = expf(alpha[tid] + gumbels[tid] - m) / s;
    }
    __syncthreads();

    // Coalesced weight loads: threads t < 16*k read w_i[p0*k + t] contiguously.
    // pair_local = t/k, tap j = t%k; tap lands at s = p + j*d.
    // Cross-array overlaps at the same (pair,s) are resolved by LDS atomics.
#define TAP(WP, I, K, P, D)                                                   \
    if (tid < PAIRS_PER_BLOCK * (K)) {                                        \
        int pl = tid / (K), j = tid % (K);                                    \
        atomicAdd(&acc[pl][(P) + j * (D)],                                    \
                  cf[I] * WP[(size_t)p0 * (K) + tid]);                        \
    }
    TAP(w0,  0, 3, 27, 1)
    TAP(w1,  1, 3, 25, 3)
    TAP(w2,  2, 3, 21, 7)
    TAP(w3,  3, 5, 26, 1)
    TAP(w4,  4, 5, 22, 3)
    TAP(w5,  5, 5, 14, 7)
    TAP(w6,  6, 7, 25, 1)
    TAP(w7,  7, 7, 19, 3)
    TAP(w8,  8, 7,  7, 7)
    TAP(w9,  9, 9, 24, 1)
    TAP(w10, 10, 9, 16, 3)
    TAP(w11, 11, 9,  0, 7)
#undef TAP
    __syncthreads();

    // Stream 16 rows x 256 float4 per block; thread tid owns slot tid of each row.
    // Only slots 0..7 and 249..255 gather nonzeros from LDS; the rest store zero.
    vfloat4* outv = reinterpret_cast<vfloat4*>(out) + (size_t)p0 * 256 + tid;
    const int slot = tid;
#pragma unroll
    for (int r = 0; r < PAIRS_PER_BLOCK; ++r) {
        const float* a = acc[r];
        vfloat4 v = (vfloat4)0.f;
        if (slot < 7) {                      // t = 4*slot..4*slot+3, s = 28-t
            int t0 = slot * 4;
            v.x = a[28 - t0]; v.y = a[27 - t0]; v.z = a[26 - t0]; v.w = a[25 - t0];
        } else if (slot == 7) {              // t=28 -> s=0; t=29..31 zero
            v.x = a[0];
        } else if (slot >= 249) {            // t=996..1023 -> s = 1052-t (29..56)
            int t0 = slot * 4;
            v.x = a[1052 - t0]; v.y = a[1051 - t0]; v.z = a[1050 - t0]; v.w = a[1049 - t0];
        }
        __builtin_nontemporal_store(v, outv + (size_t)r * 256);
    }
}

extern "C" void kernel_launch(void* const* d_in, const int* in_sizes, int n_in,
                              void* d_out, int out_size, void* d_ws, size_t ws_size,
                              hipStream_t stream) {
    multiconv_fused<<<(256 * 256) / PAIRS_PER_BLOCK, 256, 0, stream>>>(
        (const float*)d_in[0], (const float*)d_in[1], (const float*)d_in[2],
        (const float*)d_in[3], (const float*)d_in[4], (const float*)d_in[5],
        (const float*)d_in[6], (const float*)d_in[7], (const float*)d_in[8],
        (const float*)d_in[9], (const float*)d_in[10], (const float*)d_in[11],
        (const float*)d_in[12], (const float*)d_in[13], (float*)d_out);
}